// Round 21
// baseline (326.268 us; speedup 1.0000x reference)
//
#include <hip/hip_runtime.h>
#include <hip/hip_bf16.h>

// LightGCN_27384711480190 — r21: score-path made f32-source-exact.
// r19/r20 proved edge order jitters between replays -> side32 jitters ~1e-6 ->
// EPSM-boundary rows toggle between direct and f64-fixup paths. Toggles were
// harmful because direct scores carried bf16-SOURCE side error (~1e-2 tail),
// so the paths disagreed. Fix: spmm_side gathers f32 embeddings (side32 now
// matches reference f32 side to ~1e-6); direct and fixup paths agree at any
// boundary -> risky-flag toggles are invisible; tied rows go to stable f64.
#define NUQ 100000   // users
#define NIQ 50000    // items
#define NQ  150000   // N = NU + NI
#define DQ  64       // embedding dim (== wavefront)
#define GQ  4        // groups
#define EPSM 1e-2f   // argmax margin; path disagreement now ~1e-5

#define SCAN_NB  ((NQ + 255) / 256)
#define SCANB_PER ((SCAN_NB + 63) / 64)
#define FRAGU (8 * 64 * 4)                           // uints per fragment block

typedef __attribute__((ext_vector_type(8))) short bf16x8;
typedef __attribute__((ext_vector_type(4))) float f32x4;
typedef __attribute__((ext_vector_type(4))) unsigned int uint4v;

__device__ __forceinline__ unsigned f2bf(float f) {   // RNE f32 -> bf16 bits
    unsigned u = __float_as_uint(f);
    return (u + 0x7FFFu + ((u >> 16) & 1u)) >> 16;
}
__device__ __forceinline__ float bflo(unsigned w) { return __uint_as_float(w << 16); }
__device__ __forceinline__ float bfhi(unsigned w) { return __uint_as_float(w & 0xFFFF0000u); }

// ---------------------------------------------------------------------------
// CSR build. hist captures each edge's slot rank; scatter is atomic-free.
__global__ void hist_kernel(const int* __restrict__ rows, int* __restrict__ cnt,
                            int* __restrict__ rank, int nnz) {
    int e = blockIdx.x * blockDim.x + threadIdx.x;
    if (e < nnz) rank[e] = atomicAdd(&cnt[rows[e]], 1);
}

__global__ void scanA_kernel(const int* __restrict__ cnt, int* __restrict__ ofs,
                             int* __restrict__ bsum, int n) {
    int i = blockIdx.x * 256 + threadIdx.x;
    int v = (i < n) ? cnt[i] : 0;
    int lane = threadIdx.x & 63, w = threadIdx.x >> 6;
    int s = v;
    #pragma unroll
    for (int off = 1; off < 64; off <<= 1) {
        int t = __shfl_up(s, off, 64);
        if (lane >= off) s += t;
    }
    __shared__ int wsum[4];
    if (lane == 63) wsum[w] = s;
    __syncthreads();
    int add = 0;
    for (int k = 0; k < w; ++k) add += wsum[k];
    int incl = s + add;
    if (i < n) ofs[i] = incl - v;
    if (threadIdx.x == 255) bsum[blockIdx.x] = incl;
}

__global__ void scanB_kernel(int* __restrict__ bsum) {
    int lane = threadIdx.x;                 // single wave
    int base = lane * SCANB_PER;
    int local[SCANB_PER];
    int s = 0;
    #pragma unroll
    for (int k = 0; k < SCANB_PER; ++k) {
        int idx = base + k;
        int t = (idx < SCAN_NB) ? bsum[idx] : 0;
        local[k] = s;
        s += t;
    }
    int incl = s;
    #pragma unroll
    for (int off = 1; off < 64; off <<= 1) {
        int t = __shfl_up(incl, off, 64);
        if (lane >= off) incl += t;
    }
    int excl = incl - s;
    #pragma unroll
    for (int k = 0; k < SCANB_PER; ++k) {
        int idx = base + k;
        if (idx < SCAN_NB) bsum[idx] = excl + local[k];
    }
}

__global__ void scanC_kernel(int* __restrict__ ofs, const int* __restrict__ bsum,
                             int n, int nnz) {
    int i = blockIdx.x * 256 + threadIdx.x;
    if (i < n) ofs[i] += bsum[blockIdx.x];
    if (i == 0) ofs[n] = nnz;
}

// Atomic-free placement: pos = ofs[row] + precomputed rank.
__global__ void scatter_kernel(const int* __restrict__ rows,
                               const int* __restrict__ cols,
                               const float* __restrict__ vals,
                               const int* __restrict__ ofs,
                               const int* __restrict__ rank,
                               uint2* __restrict__ edge_cv, int nnz) {
    int e = blockIdx.x * blockDim.x + threadIdx.x;
    if (e >= nnz) return;
    int r = rows[e];
    int pos = ofs[r] + rank[e];
    edge_cv[pos] = make_uint2((unsigned)cols[e], __float_as_uint(vals[e]));
}

// fc_w -> bf16 MFMA B-fragments, hi block [0,FRAGU) and lo residual block.
__global__ void fc_frag_kernel(const float* __restrict__ fc_w,
                               unsigned int* __restrict__ fcfrag) {
    int i = blockIdx.x * blockDim.x + threadIdx.x;
    if (i >= FRAGU) return;
    int k = i & 3;
    int l = (i >> 2) & 63;
    int f = i >> 8;
    int t = f >> 1, q = f & 1;
    int col = t * 16 + (l & 15);
    int krow = q * 32 + ((l >> 4) << 3) + 2 * k;
    float w0 = fc_w[krow * DQ + col];
    float w1 = fc_w[(krow + 1) * DQ + col];
    unsigned h0 = f2bf(w0), h1 = f2bf(w1);
    float r0 = w0 - __uint_as_float(h0 << 16);
    float r1 = w1 - __uint_as_float(h1 << 16);
    fcfrag[i]         = h0 | (h1 << 16);
    fcfrag[FRAGU + i] = f2bf(r0) | (f2bf(r1) << 16);
}

// Mark nodes whose layer-1 planes are ever read.
__global__ void mark_needed(const int* __restrict__ users,
                            const int* __restrict__ items,
                            const int* __restrict__ ofs,
                            const uint2* __restrict__ edge_cv,
                            unsigned char* __restrict__ needed, int B) {
    int wid  = (int)(((size_t)blockIdx.x * blockDim.x + threadIdx.x) >> 6);
    int lane = threadIdx.x & 63;
    if (wid >= 2 * B) return;
    int r = (wid < B) ? users[wid] : (NUQ + items[wid - B]);
    if (lane == 0) needed[r] = 1;
    int beg = ofs[r], end = ofs[r + 1];
    for (int i = beg + lane; i < end; i += 64) needed[(int)edge_cv[i].x] = 1;
}

// ---------------------------------------------------------------------------
// SpMM side pass gathering f32 embeddings (score-path accuracy). Half-split
// lanes, 8 gathers in flight; lane j reads dims (2j,2j+1) as float2.
__global__ void spmm_side_kernel(const float* __restrict__ user_emb,
                                 const float* __restrict__ item_emb,
                                 const int* __restrict__ ofs,
                                 const uint2* __restrict__ edge_cv,
                                 unsigned int* __restrict__ sideh,
                                 float* __restrict__ side32,
                                 unsigned char* __restrict__ mask8) {
    int wid  = (int)(((size_t)blockIdx.x * blockDim.x + threadIdx.x) >> 6);
    int lane = threadIdx.x & 63;
    if (wid >= NQ) return;
    int r = wid;
    int j = lane & 31, h = lane >> 5;
    const float* ib = item_emb - (size_t)NUQ * DQ;   // ib + c*DQ valid, c>=NUQ
    int beg = ofs[r], end = ofs[r + 1];
    float acc0 = 0.f, acc1 = 0.f;     // dims (2j, 2j+1), this half's edges
    for (int base = beg; base < end; base += 64) {
        int n = end - base; if (n > 64) n = 64;
        int n1 = n - 1;
        uint2 cv = edge_cv[base + (lane < n ? lane : n1)];
        int   cc = (int)cv.x;
        float vv = __uint_as_float(cv.y);
        int npair = (n + 1) >> 1;
        for (int p = 0; p < npair; p += 8) {
            int   ccc[8];
            float vvv[8];
            #pragma unroll
            for (int u = 0; u < 8; ++u) {
                int iu = 2 * (p + u) + h;
                int ku = (iu <= n1) ? iu : n1;
                ccc[u] = __shfl(cc, ku, 64);
                float vu = __shfl(vv, ku, 64);
                vvv[u] = (iu > n1) ? 0.f : vu;
            }
            float2 ff[8];
            #pragma unroll
            for (int u = 0; u < 8; ++u) {
                const float* src = ((ccc[u] < NUQ) ? user_emb : ib)
                                   + (size_t)ccc[u] * DQ + 2 * j;
                ff[u] = *(const float2*)src;
            }
            #pragma unroll
            for (int u = 0; u < 8; ++u) {
                acc0 += vvv[u] * ff[u].x;
                acc1 += vvv[u] * ff[u].y;
            }
        }
    }
    acc0 += __shfl_xor(acc0, 32, 64);
    acc1 += __shfl_xor(acc1, 32, 64);
    if (lane < 32) {
        sideh[((size_t)r << 5) + j] = f2bf(acc0) | (f2bf(acc1) << 16);
        ((float2*)(side32 + ((size_t)r << 6)))[j] = make_float2(acc0, acc1);
    }
    if (r >= NUQ && lane == 0) mask8[r] = 0xFu;   // items: all groups
}

// ---------------------------------------------------------------------------
// Scores via bf16x3 error-compensated MFMA: x@W ~= xh@Wh + xl@Wh + xh@Wl.
__global__ __launch_bounds__(256) void scores_mfma_kernel(
        const float* __restrict__ user_emb,
        const float* __restrict__ side32,
        const unsigned int* __restrict__ fcfrag,
        const float* __restrict__ fc_b,
        const float* __restrict__ fcg_w,
        const float* __restrict__ fcg_b,
        unsigned char* __restrict__ mask8,
        unsigned char* __restrict__ risky) {
    int lane = threadIdx.x & 63;
    int wave = threadIdx.x >> 6;
    int rowbase = blockIdx.x * 64 + wave * 16;
    if (rowbase >= NUQ) return;
    int l15 = lane & 15, l4 = lane >> 4;

    int arow = rowbase + l15; if (arow >= NUQ) arow = NUQ - 1;
    union { unsigned u[4]; bf16x8 v; } ah[2], al[2];
    #pragma unroll
    for (int q = 0; q < 2; ++q) {
        int k0 = q * 32 + (l4 << 3);
        const float* ue = user_emb + (size_t)arow * DQ + k0;
        const float* sp = side32   + (size_t)arow * DQ + k0;
        #pragma unroll
        for (int kk = 0; kk < 4; ++kk) {
            float x0 = ue[2 * kk]     + sp[2 * kk];
            float x1 = ue[2 * kk + 1] + sp[2 * kk + 1];
            unsigned h0 = f2bf(x0), h1 = f2bf(x1);
            ah[q].u[kk] = h0 | (h1 << 16);
            float r0 = x0 - __uint_as_float(h0 << 16);
            float r1 = x1 - __uint_as_float(h1 << 16);
            al[q].u[kk] = f2bf(r0) | (f2bf(r1) << 16);
        }
    }
    union { uint4v u; bf16x8 v; } bh[8], bl[8];
    const uint4v* bph = (const uint4v*)fcfrag;
    const uint4v* bpl = (const uint4v*)(fcfrag + FRAGU);
    #pragma unroll
    for (int f = 0; f < 8; ++f) { bh[f].u = bph[f * 64 + lane]; bl[f].u = bpl[f * 64 + lane]; }

    float y[4][4];
    #pragma unroll
    for (int t = 0; t < 4; ++t) {
        f32x4 acc = {0.f, 0.f, 0.f, 0.f};
        acc = __builtin_amdgcn_mfma_f32_16x16x32_bf16(ah[0].v, bh[t * 2 + 0].v, acc, 0, 0, 0);
        acc = __builtin_amdgcn_mfma_f32_16x16x32_bf16(ah[1].v, bh[t * 2 + 1].v, acc, 0, 0, 0);
        acc = __builtin_amdgcn_mfma_f32_16x16x32_bf16(al[0].v, bh[t * 2 + 0].v, acc, 0, 0, 0);
        acc = __builtin_amdgcn_mfma_f32_16x16x32_bf16(al[1].v, bh[t * 2 + 1].v, acc, 0, 0, 0);
        acc = __builtin_amdgcn_mfma_f32_16x16x32_bf16(ah[0].v, bl[t * 2 + 0].v, acc, 0, 0, 0);
        acc = __builtin_amdgcn_mfma_f32_16x16x32_bf16(ah[1].v, bl[t * 2 + 1].v, acc, 0, 0, 0);
        float fb = fc_b[t * 16 + l15];
        #pragma unroll
        for (int reg = 0; reg < 4; ++reg) {
            float v = acc[reg] + fb;
            y[t][reg] = (v > 0.f) ? v : 0.01f * v;   // leaky_relu
        }
    }
    float sg[GQ][4];
    #pragma unroll
    for (int g = 0; g < GQ; ++g) {
        float w0 = fcg_w[(0 * 16 + l15) * GQ + g];
        float w1 = fcg_w[(1 * 16 + l15) * GQ + g];
        float w2 = fcg_w[(2 * 16 + l15) * GQ + g];
        float w3 = fcg_w[(3 * 16 + l15) * GQ + g];
        #pragma unroll
        for (int reg = 0; reg < 4; ++reg) {
            float v = y[0][reg] * w0 + y[1][reg] * w1 + y[2][reg] * w2 + y[3][reg] * w3;
            v += __shfl_xor(v, 1, 64);
            v += __shfl_xor(v, 2, 64);
            v += __shfl_xor(v, 4, 64);
            v += __shfl_xor(v, 8, 64);
            sg[g][reg] = v + fcg_b[g];
        }
    }
    #pragma unroll
    for (int reg = 0; reg < 4; ++reg) {
        if (l15 == reg) {
            int row = rowbase + l4 * 4 + reg;
            if (row < NUQ) {
                float s0 = sg[0][reg], s1 = sg[1][reg], s2 = sg[2][reg], s3 = sg[3][reg];
                float m = fmaxf(fmaxf(s0, s1), fmaxf(s2, s3));
                int cnt = 0, arg = 0;
                if (m - s0 < EPSM) { ++cnt; arg = 0; }
                if (m - s1 < EPSM) { ++cnt; arg = 1; }
                if (m - s2 < EPSM) { ++cnt; arg = 2; }
                if (m - s3 < EPSM) { ++cnt; arg = 3; }
                if (cnt > 1) risky[row] = 1;
                else         mask8[row] = (unsigned char)(1u << arg);
            }
        }
    }
}

// f64 fixup for near-tie rows, from ORIGINAL f32 inputs (decision-exact,
// jitter-immune at f64 precision).
__global__ void fix_risky_kernel(const float* __restrict__ user_emb,
                                 const float* __restrict__ item_emb,
                                 const float* __restrict__ fc_w,
                                 const float* __restrict__ fc_b,
                                 const float* __restrict__ fcg_w,
                                 const float* __restrict__ fcg_b,
                                 const int* __restrict__ ofs,
                                 const uint2* __restrict__ edge_cv,
                                 const unsigned char* __restrict__ risky,
                                 unsigned char* __restrict__ mask8) {
    int wid  = (int)(((size_t)blockIdx.x * blockDim.x + threadIdx.x) >> 6);
    int lane = threadIdx.x & 63;
    if (wid >= NUQ) return;
    int r = wid;
    if (!risky[r]) return;
    const float* ib = item_emb - (size_t)NUQ * DQ;
    int beg = ofs[r], end = ofs[r + 1];
    double a = 0.0;
    for (int i = beg; i < end; ++i) {
        uint2 cv = edge_cv[i];
        int c = (int)cv.x;
        const float* p = ((c < NUQ) ? user_emb : ib) + (size_t)c * DQ;
        a += (double)__uint_as_float(cv.y) * (double)p[lane];
    }
    double x = (double)user_emb[(size_t)r * DQ + lane] + a;
    double t = (double)fc_b[lane];
    for (int k = 0; k < DQ; ++k)
        t += __shfl(x, k, 64) * (double)fc_w[k * DQ + lane];
    t = (t > 0.0) ? t : 0.01 * t;
    double sg[GQ];
    #pragma unroll
    for (int g = 0; g < GQ; ++g) {
        double v2 = t * (double)fcg_w[lane * GQ + g];
        #pragma unroll
        for (int off = 32; off > 0; off >>= 1) v2 += __shfl_xor(v2, off, 64);
        sg[g] = v2 + (double)fcg_b[g];
    }
    double m = fmax(fmax(sg[0], sg[1]), fmax(sg[2], sg[3]));
    unsigned bits = 0;
    #pragma unroll
    for (int g = 0; g < GQ; ++g) if (sg[g] == m) bits |= (1u << g);
    if (lane == 0) mask8[r] = (unsigned char)bits;
}

// ---------------------------------------------------------------------------
// Layer 1 for needed rows, gathering bf16 side. emb4 layout [N][4][64] f32.
// Single-group path 8-deep; multi-group (item) path 4-deep.
__global__ void layer1_kernel(const int* __restrict__ ofs,
                              const uint2* __restrict__ edge_cv,
                              const unsigned char* __restrict__ mask8,
                              const unsigned char* __restrict__ needed,
                              const unsigned int* __restrict__ sideh,
                              float* __restrict__ emb4) {
    int wid  = (int)(((size_t)blockIdx.x * blockDim.x + threadIdx.x) >> 6);
    int lane = threadIdx.x & 63;
    if (wid >= NQ) return;
    int r = wid;
    if (!needed[r]) return;
    unsigned mr = mask8[r];
    int j = lane & 31, h = lane >> 5;
    int beg = ofs[r], end = ofs[r + 1];
    bool single = (mr & (mr - 1u)) == 0u;

    if (single) {
        float acc0 = 0.f, acc1 = 0.f;
        for (int base = beg; base < end; base += 64) {
            int n = end - base; if (n > 64) n = 64;
            int n1 = n - 1;
            uint2 cv = edge_cv[base + (lane < n ? lane : n1)];
            int   cc = (int)cv.x;
            float vv = __uint_as_float(cv.y);
            int pack = cc | ((int)(mr & (unsigned)mask8[cc]) << 20);
            int npair = (n + 1) >> 1;
            for (int p = 0; p < npair; p += 8) {
                int   www[8];
                float vvv[8];
                #pragma unroll
                for (int u = 0; u < 8; ++u) {
                    int iu = 2 * (p + u) + h;
                    int ku = (iu <= n1) ? iu : n1;
                    www[u] = __shfl(pack, ku, 64);
                    float vu = __shfl(vv, ku, 64);
                    vvv[u] = (iu > n1 || !((unsigned)www[u] >> 20)) ? 0.f : vu;
                }
                unsigned ee[8];
                #pragma unroll
                for (int u = 0; u < 8; ++u)
                    ee[u] = sideh[((size_t)(www[u] & 0xFFFFF) << 5) + j];
                #pragma unroll
                for (int u = 0; u < 8; ++u) {
                    acc0 += vvv[u] * bflo(ee[u]);
                    acc1 += vvv[u] * bfhi(ee[u]);
                }
            }
        }
        acc0 += __shfl_xor(acc0, 32, 64);
        acc1 += __shfl_xor(acc1, 32, 64);
        int p = __ffs((int)mr) - 1;
        if (lane < 32) {
            float2* dst = (float2*)(emb4 + (((size_t)r * GQ + p) << 6));
            dst[j] = make_float2(acc0, acc1);
        }
    } else {
        float b0 = 0.f, b1 = 0.f, b2 = 0.f, b3 = 0.f;   // dim 2j, planes 0-3
        float d0 = 0.f, d1 = 0.f, d2 = 0.f, d3 = 0.f;   // dim 2j+1
        for (int base = beg; base < end; base += 64) {
            int n = end - base; if (n > 64) n = 64;
            int n1 = n - 1;
            uint2 cv = edge_cv[base + (lane < n ? lane : n1)];
            int   cc = (int)cv.x;
            float vv = __uint_as_float(cv.y);
            int pack = cc | ((int)(mr & (unsigned)mask8[cc]) << 20);
            int npair = (n + 1) >> 1;
            for (int p = 0; p < npair; p += 4) {
                int   www[4];
                float vvv[4];
                #pragma unroll
                for (int u = 0; u < 4; ++u) {
                    int iu = 2 * (p + u) + h;
                    int ku = (iu <= n1) ? iu : n1;
                    www[u] = __shfl(pack, ku, 64);
                    float vu = __shfl(vv, ku, 64);
                    vvv[u] = (iu > n1) ? 0.f : vu;
                }
                unsigned ee[4];
                #pragma unroll
                for (int u = 0; u < 4; ++u)
                    ee[u] = sideh[((size_t)(www[u] & 0xFFFFF) << 5) + j];
                #pragma unroll
                for (int u = 0; u < 4; ++u) {
                    unsigned mb = (unsigned)www[u] >> 20;
                    float f0 = vvv[u] * bflo(ee[u]);
                    float f1 = vvv[u] * bfhi(ee[u]);
                    b0 += (mb & 1u) ? f0 : 0.f;  d0 += (mb & 1u) ? f1 : 0.f;
                    b1 += (mb & 2u) ? f0 : 0.f;  d1 += (mb & 2u) ? f1 : 0.f;
                    b2 += (mb & 4u) ? f0 : 0.f;  d2 += (mb & 4u) ? f1 : 0.f;
                    b3 += (mb & 8u) ? f0 : 0.f;  d3 += (mb & 8u) ? f1 : 0.f;
                }
            }
        }
        b0 += __shfl_xor(b0, 32, 64);  d0 += __shfl_xor(d0, 32, 64);
        b1 += __shfl_xor(b1, 32, 64);  d1 += __shfl_xor(d1, 32, 64);
        b2 += __shfl_xor(b2, 32, 64);  d2 += __shfl_xor(d2, 32, 64);
        b3 += __shfl_xor(b3, 32, 64);  d3 += __shfl_xor(d3, 32, 64);
        if (lane < 32) {
            float2* dst = (float2*)(emb4 + (((size_t)r * GQ) << 6));
            dst[j]      = make_float2(b0, d0);
            dst[j + 32] = make_float2(b1, d1);
            dst[j + 64] = make_float2(b2, d2);
            dst[j + 96] = make_float2(b3, d3);
        }
    }
}

// ---------------------------------------------------------------------------
// Fused layer2 + gamma, sampled rows only.
__device__ __forceinline__ float l2_row(int r, int lane, unsigned mr,
                                        const int* __restrict__ ofs,
                                        const uint2* __restrict__ edge_cv,
                                        const unsigned char* __restrict__ mask8,
                                        const float* __restrict__ emb4) {
    float sum = 0.f;
    int beg = ofs[r], end = ofs[r + 1];
    for (int base = beg; base < end; base += 64) {
        int n = end - base; if (n > 64) n = 64;
        int n1 = n - 1;
        uint2 cv = edge_cv[base + (lane < n ? lane : n1)];
        int   cc = (int)cv.x;
        float vv = __uint_as_float(cv.y);
        int pack = cc | ((int)(mr & (unsigned)mask8[cc]) << 20);
        for (int e = 0; e < n; ++e) {
            int w = __shfl(pack, e, 64);
            unsigned mb = ((unsigned)w >> 20) & 0xFu;
            if (!mb) continue;
            float v = __shfl(vv, e, 64);
            size_t co = (size_t)(w & 0xFFFFF) * (GQ * DQ) + lane;
            if (mb == 0xFu) {
                sum += v * (emb4[co] + emb4[co + DQ] + emb4[co + 2 * DQ] + emb4[co + 3 * DQ]);
            } else if ((mb & (mb - 1u)) == 0u) {
                sum += v * emb4[co + ((__ffs((int)mb) - 1) << 6)];
            } else {
                #pragma unroll
                for (int g = 0; g < GQ; ++g)
                    if ((mb >> g) & 1u) sum += v * emb4[co + (g << 6)];
            }
        }
    }
    return sum;
}

__global__ void gamma_kernel(const int* __restrict__ ofs,
                             const uint2* __restrict__ edge_cv,
                             const unsigned char* __restrict__ mask8,
                             const float* __restrict__ side32,
                             const float* __restrict__ emb4,
                             const int* __restrict__ users,
                             const int* __restrict__ items,
                             float* __restrict__ out, int B) {
    int wid  = (int)(((size_t)blockIdx.x * blockDim.x + threadIdx.x) >> 6);
    int lane = threadIdx.x & 63;
    if (wid >= B) return;
    int u  = users[wid];
    int it = NUQ + items[wid];
    unsigned mu = mask8[u];
    size_t uo = (size_t)u * GQ * DQ + lane;
    size_t io = (size_t)it * GQ * DQ + lane;
    float baseu = 0.f;
    #pragma unroll
    for (int g = 0; g < GQ; ++g)
        if ((mu >> g) & 1u) baseu += emb4[uo + (g << 6)];
    float basei = emb4[io] + emb4[io + DQ] + emb4[io + 2 * DQ] + emb4[io + 3 * DQ];
    float su = side32[(size_t)u * DQ + lane];
    float si = side32[(size_t)it * DQ + lane];
    float fu = 4.f * su + baseu + l2_row(u, lane, mu, ofs, edge_cv, mask8, emb4);
    float fi = 4.f * si + basei + l2_row(it, lane, 0xFu, ofs, edge_cv, mask8, emb4);
    float p = fu * fi;
    #pragma unroll
    for (int off = 32; off > 0; off >>= 1) p += __shfl_xor(p, off, 64);
    if (lane == 0) out[wid] = 0.04f * p;   // 0.2^2
}

// ---------------------------------------------------------------------------
extern "C" void kernel_launch(void* const* d_in, const int* in_sizes, int n_in,
                              void* d_out, int out_size, void* d_ws, size_t ws_size,
                              hipStream_t stream) {
    const float* user_emb = (const float*)d_in[0];
    const float* item_emb = (const float*)d_in[1];
    const float* fc_w     = (const float*)d_in[2];
    const float* fc_b     = (const float*)d_in[3];
    const float* fcg_w    = (const float*)d_in[4];
    const float* fcg_b    = (const float*)d_in[5];
    const float* vals     = (const float*)d_in[6];
    const int*   rows     = (const int*)d_in[7];
    const int*   cols     = (const int*)d_in[8];
    const int*   users    = (const int*)d_in[9];
    const int*   items    = (const int*)d_in[10];
    const int nnz = in_sizes[6];
    const int B   = in_sizes[9];
    float* out = (float*)d_out;

    const size_t ND = (size_t)NQ * DQ;

    char* ws = (char*)d_ws;
    size_t off = 0;
    float* emb4 = (float*)(ws + off); off += 4 * ND * sizeof(float);           // 153.6 MB
    unsigned int* sideh = (unsigned int*)(ws + off); off += ND * 2;            //  19.2 MB
    float* side32 = (float*)(ws + off); off += ND * sizeof(float);             //  38.4 MB
    uint2* edge_cv = (uint2*)(ws + off); off += (size_t)nnz * 8;               //  16.0 MB
    int* rank     = (int*)(ws + off); off += (size_t)nnz * 4;                  //   8.0 MB
    int* row_ofs  = (int*)(ws + off); off += ((size_t)(NQ + 1) * 4 + 255) / 256 * 256;
    int* bsum     = (int*)(ws + off); off += ((size_t)SCAN_NB * 4 + 255) / 256 * 256;
    unsigned int* fcfrag = (unsigned int*)(ws + off); off += 2 * FRAGU * 4;    //  16 KB
    // contiguous zero-init block: row_cnt, needed/risky bytes
    char* zblock = ws + off;
    int* row_cnt  = (int*)(ws + off); off += (size_t)NQ * 4;
    unsigned char* needed = (unsigned char*)(ws + off); off += ((size_t)NQ + 255) / 256 * 256;
    unsigned char* risky  = (unsigned char*)(ws + off); off += ((size_t)NUQ + 255) / 256 * 256;
    size_t zbytes = (size_t)(ws + off - zblock);
    unsigned char* mask8  = (unsigned char*)(ws + off); off += ((size_t)NQ + 255) / 256 * 256;

    // --- CSR build: rank-capturing hist -> scan -> atomic-free scatter ---
    hipMemsetAsync(zblock, 0, zbytes, stream);
    hist_kernel<<<(nnz + 255) / 256, 256, 0, stream>>>(rows, row_cnt, rank, nnz);
    scanA_kernel<<<SCAN_NB, 256, 0, stream>>>(row_cnt, row_ofs, bsum, NQ);
    scanB_kernel<<<1, 64, 0, stream>>>(bsum);
    scanC_kernel<<<SCAN_NB, 256, 0, stream>>>(row_ofs, bsum, NQ, nnz);
    scatter_kernel<<<(nnz + 255) / 256, 256, 0, stream>>>(rows, cols, vals,
                                                          row_ofs, rank,
                                                          edge_cv, nnz);
    fc_frag_kernel<<<8, 256, 0, stream>>>(fc_w, fcfrag);
    mark_needed<<<(2 * B * 64 + 255) / 256, 256, 0, stream>>>(
        users, items, row_ofs, edge_cv, needed, B);

    // --- side SpMM (all rows, f32 gathers) ---
    const int row_blocks = (NQ * 64 + 255) / 256;   // 4 waves/block
    spmm_side_kernel<<<row_blocks, 256, 0, stream>>>(user_emb, item_emb,
                                                     row_ofs, edge_cv,
                                                     sideh, side32, mask8);

    // --- user scores via bf16x3 MFMA -> masks (+risky) ---
    scores_mfma_kernel<<<(NUQ + 63) / 64, 256, 0, stream>>>(
        user_emb, side32, fcfrag, fc_b, fcg_w, fcg_b, mask8, risky);
    fix_risky_kernel<<<(NUQ * 64 + 255) / 256, 256, 0, stream>>>(
        user_emb, item_emb, fc_w, fc_b, fcg_w, fcg_b,
        row_ofs, edge_cv, risky, mask8);

    // --- layer 1 (needed rows only) ---
    layer1_kernel<<<row_blocks, 256, 0, stream>>>(row_ofs, edge_cv, mask8,
                                                  needed, sideh, emb4);

    // --- fused layer2 + gamma (sampled rows only) ---
    gamma_kernel<<<((size_t)B * 64 + 255) / 256, 256, 0, stream>>>(
        row_ofs, edge_cv, mask8, side32, emb4, users, items, out, B);
}